// Round 21
// baseline (2412.302 us; speedup 1.0000x reference)
//
#include <hip/hip_runtime.h>

// LSTM_88776974008866: bidirectional LSTM (B=2048, S=128, H=512, in=4) + 4 sigmoid heads.
// Round 21: r20 (1451us) + WAVE-LEVEL TWO-PHASE POLL (no barriers -- r17's block-level
// version failed because of its extra __syncthreads; rings have none). Slice s is
// produced by ranks {2s,2s+1}; consumption order is SL(i)=(rank+i)&15. Phase A polls
// only the 16 producers of slices SL(0..7); iterations 0..3 run (prefetch <= SL(7));
// phase B polls the 16 producers of SL(8..15) (flags got ~2us extra -> one-shot),
// then iterations 4..15. No inv at phase B: those lines untouched since the step inv.
// Accumulation order unchanged => absmax must stay exactly 0.00390625.
// LEDGER: 1 protocol-block/CU (r9/r14); no agent acquire/release in hot loop (r3/r4/r5);
// full-64B-line h writes via chunk layout (r12); VGPR headroom (r10/r15); XCD groups via
// HW_REG_XCC_ID rank (r7); per-(block,wave) rings, no __syncthreads in loop (r19).

typedef __attribute__((ext_vector_type(8))) __bf16 bf16x8;
typedef __attribute__((ext_vector_type(4))) float f32x4;
typedef __attribute__((ext_vector_type(8))) unsigned short u16x8;

__device__ __forceinline__ unsigned short f2bf(float f) {
  unsigned u = __float_as_uint(f);
  u += 0x7fffu + ((u >> 16) & 1u);   // round-to-nearest-even
  return (unsigned short)(u >> 16);
}
__device__ __forceinline__ float bf2f(unsigned short s) {
  return __uint_as_float(((unsigned)s) << 16);
}
__device__ __forceinline__ float sigm(float x) { return 1.0f / (1.0f + __expf(-x)); }
__device__ __forceinline__ float tanhfast(float x) {
  float e = __expf(-2.0f * fabsf(x));
  float t = (1.0f - e) / (1.0f + e);
  return x < 0.0f ? -t : t;
}

__device__ __forceinline__ void gl_lds16(const void* g, void* l) {
  __builtin_amdgcn_global_load_lds(
      (const __attribute__((address_space(1))) unsigned int*)g,
      (__attribute__((address_space(3))) unsigned int*)l, 16, 0, 0);
}

// ---------------------------------------------------------------------------
// prep (r18 verbatim): Whh -> per-(dir,band) 68KB images, 17 K-slices.
// ---------------------------------------------------------------------------
__global__ __launch_bounds__(256) void prep_k(
    const float* __restrict__ Wf_hh, const float* __restrict__ Wf_ih,
    const float* __restrict__ bf_ih, const float* __restrict__ bf_hh,
    const float* __restrict__ Wb_hh, const float* __restrict__ Wb_ih,
    const float* __restrict__ bb_ih, const float* __restrict__ bb_hh,
    unsigned short* __restrict__ Wimg)
{
  int flat = blockIdx.x * 256 + threadIdx.x;   // 0 .. 278527
  int lane = flat & 63;
  int nf = (flat >> 6) & 3;
  int q = flat >> 8;                           // (dir*32+band)*17 + kt
  int kt = q % 17;
  int dn = q / 17;                             // 0..63
  int band = dn & 31;
  int dir = dn >> 5;
  int l15 = lane & 15, lhi = lane >> 4;
  const float* Whh = dir ? Wb_hh : Wf_hh;
  const float* Wih = dir ? Wb_ih : Wf_ih;
  const float* bih = dir ? bb_ih : bf_ih;
  const float* bhh = dir ? bb_hh : bf_hh;

  int j = (band << 4) + l15;                   // hidden index 0..511
  int orig = (nf << 9) + j;                    // gate-major row in [0,2048)

  u16x8 o = {};
  if (kt < 16) {
    int k0 = (kt << 5) + (lhi << 3);
    const float4* src = (const float4*)(Whh + (size_t)orig * 512 + k0);
    float4 a = src[0], b = src[1];
    o[0] = f2bf(a.x); o[1] = f2bf(a.y); o[2] = f2bf(a.z); o[3] = f2bf(a.w);
    o[4] = f2bf(b.x); o[5] = f2bf(b.y); o[6] = f2bf(b.z); o[7] = f2bf(b.w);
  } else if (lhi == 0) {
    o[0] = f2bf(Wih[orig * 4 + 0]);
    o[1] = f2bf(Wih[orig * 4 + 1]);
    o[2] = f2bf(Wih[orig * 4 + 2]);
    o[3] = f2bf(Wih[orig * 4 + 3]);
    o[4] = f2bf(bih[orig] + bhh[orig]);
  }
  *(u16x8*)(Wimg + (size_t)flat * 8) = o;
}

// ---------------------------------------------------------------------------
// prep_x: xt[t][b][8] = {bf16(x0..x3), 1.0, 0,0,0} -- per-step tail A fragment.
// ---------------------------------------------------------------------------
__global__ __launch_bounds__(256) void prep_x(
    const float* __restrict__ y, unsigned short* __restrict__ xt)
{
  int flat = blockIdx.x * 256 + threadIdx.x;   // t*2048 + b, 0..262143
  int b = flat & 2047;
  int t = flat >> 11;
  float4 x4 = ((const float4*)y)[(size_t)b * 128 + t];
  u16x8 o = {};
  o[0] = f2bf(x4.x); o[1] = f2bf(x4.y); o[2] = f2bf(x4.z); o[3] = f2bf(x4.w);
  o[4] = 0x3F80;   // 1.0 -> picks up bias row
  *(u16x8*)(xt + (size_t)flat * 8) = o;
}

__device__ __forceinline__ void mfma8(const bf16x8 av[2], const bf16x8 bv[4],
                                      f32x4 acc[2][4]) {
#pragma unroll
  for (int mf = 0; mf < 2; ++mf)
#pragma unroll
    for (int nf = 0; nf < 4; ++nf)
      acc[mf][nf] = __builtin_amdgcn_mfma_f32_16x16x32_bf16(av[mf], bv[nf], acc[mf][nf], 0, 0, 0);
}

// ---------------------------------------------------------------------------
// Persistent kernel: 256 blocks x 512 threads (1 block/CU via 136KB LDS),
// cooperative launch => exactly 32 blocks per XCD. rank 0..31 = column band.
// h buffers in CHUNK layout: (b,j) at short-index (j>>3)*16384 + b*8 + (j&7).
// Sync: per-(block,wave) flags -> 8 independent 32-wave rings per XCD, polled
// in two phases (slices SL(0..7) then SL(8..15)).
// ctrl (uints): [xcc<<5] rank counters; flags at 256 + ((xcc*8+w)*32 + rank)*32.
// ---------------------------------------------------------------------------
__global__ __launch_bounds__(512, 2) void lstm_persist(
    const unsigned short* __restrict__ xt,
    const unsigned short* __restrict__ Wp,
    unsigned short* __restrict__ hf0, unsigned short* __restrict__ hf1,
    unsigned short* __restrict__ hb0, unsigned short* __restrict__ hb1,
    unsigned* __restrict__ ctrl)
{
  __shared__ alignas(16) unsigned short Wl[69632];   // 136KB: fwd 68KB | bwd 68KB
  __shared__ unsigned rank_sh;

  const int tid = threadIdx.x;
  const int w = tid >> 6, lane = tid & 63;
  const int l15 = lane & 15, lhi = lane >> 4;

  unsigned xcc;
  asm("s_getreg_b32 %0, hwreg(HW_REG_XCC_ID)" : "=s"(xcc));
  xcc &= 7u;

  if (tid == 0) {
    rank_sh = __hip_atomic_fetch_add(ctrl + (xcc << 5), 1u,
                                     __ATOMIC_RELAXED, __HIP_MEMORY_SCOPE_AGENT);
  }
  __syncthreads();
  const int rank = (int)(rank_sh & 31u);   // column band, both dirs
  const int bm0 = (int)xcc << 8;           // this XCD's 256 batch rows

  // ---- one-time: stage both 68KB W images into LDS (17 x 8KB rounds) ----
  for (int i = 0; i < 17; ++i) {
    int c0 = (i << 9) + (w << 6);          // wave-uniform chunk base (4352 % 64 == 0)
    const unsigned short* src =
        (c0 < 4352) ? Wp + ((size_t)rank * 4352 + c0 + lane) * 8
                    : Wp + ((size_t)(32 + rank) * 4352 + (c0 - 4352) + lane) * 8;
    gl_lds16(src, (unsigned short*)Wl + (size_t)c0 * 8);
  }

  float c_reg[16];                          // [dir*8 + mf*4 + r]
#pragma unroll
  for (int i = 0; i < 16; ++i) c_reg[i] = 0.f;

  // per-(xcc, wave) ring of 32 flags, 128B apart
  unsigned* wflags = ctrl + 256 + ((((unsigned)xcc << 3) | (unsigned)w) << 10);
  unsigned* myflag = wflags + ((unsigned)rank << 5);       // single writer

  // two-phase poll flag addresses (lanes 0-15): producers of slices SL(0..7)/SL(8..15)
  const unsigned* fpA = wflags +
      (((2u * (unsigned)((rank + (lane >> 1)) & 15) + (unsigned)(lane & 1))) << 5);
  const unsigned* fpB = wflags +
      (((2u * (unsigned)((rank + 8 + (lane >> 1)) & 15) + (unsigned)(lane & 1))) << 5);

  const unsigned short* wBf = Wl + (lane << 3);            // fwd image base
  const unsigned short* wBb = Wl + 34816 + (lane << 3);    // bwd image base

  __syncthreads();   // Wl ready (drains global_load_lds) -- the ONLY block barrier

#pragma unroll 1
  for (int t = 0; t < 128; ++t) {
    const unsigned short* hf_in = (t & 1) ? hf1 : hf0;
    unsigned short* hf_out      = (t & 1) ? hf0 : hf1;
    const unsigned short* hb_in = (t & 1) ? hb1 : hb0;
    unsigned short* hb_out      = (t & 1) ? hb0 : hb1;

    // ---- tail MFMAs BEFORE the poll (pre-converted xt + B-slice 16 from LDS) ----
    f32x4 accF[2][4], accB[2][4];
#pragma unroll
    for (int a = 0; a < 2; ++a)
#pragma unroll
      for (int b = 0; b < 4; ++b) {
        accF[a][b] = (f32x4){0.f, 0.f, 0.f, 0.f};
        accB[a][b] = (f32x4){0.f, 0.f, 0.f, 0.f};
      }
    {
      bf16x8 atf[2], atb[2], btf[4], btb[4];
      u16x8 z = {};
#pragma unroll
      for (int mf = 0; mf < 2; ++mf) {
        const size_t row = (size_t)(bm0 + (w << 5) + (mf << 4) + l15);
        u16x8 vf = *(const u16x8*)(xt + (((size_t)t << 11) + row) * 8);
        u16x8 vb = *(const u16x8*)(xt + (((size_t)(127 - t) << 11) + row) * 8);
        u16x8 sf = (lhi == 0) ? vf : z;
        u16x8 sb = (lhi == 0) ? vb : z;
        atf[mf] = *(bf16x8*)&sf;
        atb[mf] = *(bf16x8*)&sb;
      }
#pragma unroll
      for (int nf = 0; nf < 4; ++nf) {
        btf[nf] = *(const bf16x8*)(wBf + (16 << 11) + (nf << 9));
        btb[nf] = *(const bf16x8*)(wBb + (16 << 11) + (nf << 9));
      }
      mfma8(atf, btf, accF);
      mfma8(atb, btb, accB);
    }

    if (t) {
      // ---- phase-A poll: 16 flags covering slices SL(0..7) ----
      while (true) {
        unsigned v = 0;
        if (lane < 16)
          v = __hip_atomic_load(fpA, __ATOMIC_RELAXED, __HIP_MEMORY_SCOPE_AGENT);
        bool ok = (lane < 16) ? (v >= (unsigned)t) : true;
        if (__all(ok)) break;
        __builtin_amdgcn_s_sleep(1);
      }
      asm volatile("buffer_inv sc0\n\ts_waitcnt vmcnt(0)" ::: "memory");

      // A bases in chunk layout: frag (kt, mf) at base + kt*65536 + mf*128 shorts
      const size_t abase = (size_t)lhi * 16384 + (size_t)(bm0 + (w << 5) + l15) * 8;
      const unsigned short* aFb = hf_in + abase;
      const unsigned short* aBb_ = hb_in + abase;

      bf16x8 aF[4][2], aB[4][2], bF[2][4], bB[2][4];   // A ring depth 4

#define SL(i) ((rank + (i)) & 15)
#define ALOADF(kk, sl)                                                         \
      do { const unsigned short* p_ = aFb + (size_t)(kk) * 65536;              \
        aF[sl][0] = *(const bf16x8*)(p_);                                      \
        aF[sl][1] = *(const bf16x8*)(p_ + 128); } while (0)
#define ALOADB(kk, sl)                                                         \
      do { const unsigned short* p_ = aBb_ + (size_t)(kk) * 65536;             \
        aB[sl][0] = *(const bf16x8*)(p_);                                      \
        aB[sl][1] = *(const bf16x8*)(p_ + 128); } while (0)
#define BLOADF(kk, sl)                                                         \
      do { const unsigned short* p_ = wBf + ((kk) << 11);                      \
        bF[sl][0] = *(const bf16x8*)(p_);                                      \
        bF[sl][1] = *(const bf16x8*)(p_ + 512);                                \
        bF[sl][2] = *(const bf16x8*)(p_ + 1024);                               \
        bF[sl][3] = *(const bf16x8*)(p_ + 1536); } while (0)
#define BLOADB(kk, sl)                                                         \
      do { const unsigned short* p_ = wBb + ((kk) << 11);                      \
        bB[sl][0] = *(const bf16x8*)(p_);                                      \
        bB[sl][1] = *(const bf16x8*)(p_ + 512);                                \
        bB[sl][2] = *(const bf16x8*)(p_ + 1024);                               \
        bB[sl][3] = *(const bf16x8*)(p_ + 1536); } while (0)

      ALOADF(SL(0), 0); ALOADB(SL(0), 0);
      ALOADF(SL(1), 1); ALOADB(SL(1), 1);
      ALOADF(SL(2), 2); ALOADB(SL(2), 2);
      ALOADF(SL(3), 3); ALOADB(SL(3), 3);
      BLOADF(SL(0), 0); BLOADB(SL(0), 0);
      BLOADF(SL(1), 1); BLOADB(SL(1), 1);

      // ---- iterations 0..3: consume SL(0..3), prefetch SL(4..7) (phase-A set) ----
#pragma unroll
      for (int i = 0; i < 4; ++i) {
        __builtin_amdgcn_s_setprio(1);
        mfma8(aF[i & 3], bF[i & 1], accF);
        __builtin_amdgcn_s_setprio(0);
        ALOADF(SL(i + 4), (i + 4) & 3);
        BLOADF(SL(i + 2), i & 1);
        __builtin_amdgcn_s_setprio(1);
        mfma8(aB[i & 3], bB[i & 1], accB);
        __builtin_amdgcn_s_setprio(0);
        ALOADB(SL(i + 4), (i + 4) & 3);
        BLOADB(SL(i + 2), i & 1);
      }

      // ---- phase-B poll: 16 flags covering slices SL(8..15) (~2us extra time;
      //      lines untouched since the step inv -> no second inv needed) ----
      while (true) {
        unsigned v = 0;
        if (lane < 16)
          v = __hip_atomic_load(fpB, __ATOMIC_RELAXED, __HIP_MEMORY_SCOPE_AGENT);
        bool ok = (lane < 16) ? (v >= (unsigned)t) : true;
        if (__all(ok)) break;
        __builtin_amdgcn_s_sleep(1);
      }
      asm volatile("" ::: "memory");   // pin later A-loads after the poll

      // ---- iterations 4..15: consume SL(4..15), prefetch SL(8..15) ----
#pragma unroll
      for (int i = 4; i < 16; ++i) {
        __builtin_amdgcn_s_setprio(1);
        mfma8(aF[i & 3], bF[i & 1], accF);
        __builtin_amdgcn_s_setprio(0);
        if (i < 12) ALOADF(SL(i + 4), (i + 4) & 3);
        if (i < 14) BLOADF(SL(i + 2), i & 1);
        __builtin_amdgcn_s_setprio(1);
        mfma8(aB[i & 3], bB[i & 1], accB);
        __builtin_amdgcn_s_setprio(0);
        if (i < 12) ALOADB(SL(i + 4), (i + 4) & 3);
        if (i < 14) BLOADB(SL(i + 2), i & 1);
      }
#undef ALOADF
#undef ALOADB
#undef BLOADF
#undef BLOADB
#undef SL
    }

    // ---- epilogues: lane-local cell updates; chunk-layout h stores ----
    // (b, j=rank*16+l15) -> (2*rank + (l15>>3))*16384 + b*8 + (l15&7)
    {
      const size_t cbase = (size_t)((rank << 1) + (l15 >> 3)) * 16384 + (size_t)(l15 & 7);
#pragma unroll
      for (int mf = 0; mf < 2; ++mf) {
#pragma unroll
        for (int r = 0; r < 4; ++r) {
          const int b = bm0 + (w << 5) + (mf << 4) + (lhi << 2) + r;
          // fwd
          {
            const float ig = sigm(accF[mf][0][r]);
            const float fg = sigm(accF[mf][1][r]);
            const float gg = tanhfast(accF[mf][2][r]);
            const float og = sigm(accF[mf][3][r]);
            const float cn = fg * c_reg[(mf << 2) + r] + ig * gg;
            c_reg[(mf << 2) + r] = cn;
            hf_out[cbase + (size_t)b * 8] = f2bf(og * tanhfast(cn));
          }
          // bwd
          {
            const float ig = sigm(accB[mf][0][r]);
            const float fg = sigm(accB[mf][1][r]);
            const float gg = tanhfast(accB[mf][2][r]);
            const float og = sigm(accB[mf][3][r]);
            const float cn = fg * c_reg[8 + (mf << 2) + r] + ig * gg;
            c_reg[8 + (mf << 2) + r] = cn;
            hb_out[cbase + (size_t)b * 8] = f2bf(og * tanhfast(cn));
          }
        }
      }
    }

    // ---- publish: drain OWN stores -> lane0 bumps OWN (block,wave) flag ----
    if (t != 127) {
      asm volatile("s_waitcnt vmcnt(0)" ::: "memory");   // own h stores in L2
      if (lane == 0) {
        __hip_atomic_fetch_add(myflag, 1u, __ATOMIC_RELAXED,
                               __HIP_MEMORY_SCOPE_AGENT);
      }
    }
  }
}

// ---------------------------------------------------------------------------
// heads: out[b][k] = sigmoid(hf[b]·Wk[0:512] + hb[b]·Wk[512:1024] + bk)
// h buffers in chunk layout: (b,j) at (j>>3)*16384 + b*8 + (j&7).
// ---------------------------------------------------------------------------
__global__ __launch_bounds__(256) void heads_k(
    const unsigned short* __restrict__ hf, const unsigned short* __restrict__ hb,
    const float* __restrict__ W1, const float* __restrict__ b1,
    const float* __restrict__ W2, const float* __restrict__ b2,
    const float* __restrict__ W3, const float* __restrict__ b3,
    const float* __restrict__ W4, const float* __restrict__ b4,
    float* __restrict__ out)
{
  const int wid = threadIdx.x >> 6, lane = threadIdx.x & 63;
  const int b = blockIdx.x * 4 + wid;
  const unsigned short* src = (lane < 32) ? hf : hb;
  const int ll = (lane < 32) ? lane : (lane - 32);
  u16x8 v0 = *(const u16x8*)(src + (size_t)(2 * ll) * 16384 + (size_t)b * 8);
  u16x8 v1 = *(const u16x8*)(src + (size_t)(2 * ll + 1) * 16384 + (size_t)b * 8);
  const int woff = lane << 4;
  float hv[16];
#pragma unroll
  for (int e = 0; e < 8; ++e) { hv[e] = bf2f(v0[e]); hv[8 + e] = bf2f(v1[e]); }
  float s0 = 0.f, s1 = 0.f, s2 = 0.f, s3 = 0.f;
#pragma unroll
  for (int e = 0; e < 16; ++e) {
    float h = hv[e];
    s0 += h * W1[woff + e];
    s1 += h * W2[woff + e];
    s2 += h * W3[woff + e];
    s3 += h * W4[woff + e];
  }
#pragma unroll
  for (int off = 32; off >= 1; off >>= 1) {
    s0 += __shfl_xor(s0, off, 64);
    s1 += __shfl_xor(s1, off, 64);
    s2 += __shfl_xor(s2, off, 64);
    s3 += __shfl_xor(s3, off, 64);
  }
  if (lane == 0) {
    out[b * 4 + 0] = sigm(s0 + b1[0]);
    out[b * 4 + 1] = sigm(s1 + b2[0]);
    out[b * 4 + 2] = sigm(s2 + b3[0]);
    out[b * 4 + 3] = sigm(s3 + b4[0]);
  }
}

// ---------------------------------------------------------------------------
extern "C" void kernel_launch(void* const* d_in, const int* in_sizes, int n_in,
                              void* d_out, int out_size, void* d_ws, size_t ws_size,
                              hipStream_t stream) {
  (void)in_sizes; (void)n_in; (void)out_size; (void)ws_size;
  const float* y     = (const float*)d_in[0];
  const float* Wf_ih = (const float*)d_in[1];
  const float* Wf_hh = (const float*)d_in[2];
  const float* bf_ih = (const float*)d_in[3];
  const float* bf_hh = (const float*)d_in[4];
  const float* Wb_ih = (const float*)d_in[5];
  const float* Wb_hh = (const float*)d_in[6];
  const float* bb_ih = (const float*)d_in[7];
  const float* bb_hh = (const float*)d_in[8];
  const float* W1 = (const float*)d_in[9];  const float* b1 = (const float*)d_in[10];
  const float* W2 = (const float*)d_in[11]; const float* b2 = (const float*)d_in[12];
  const float* W3 = (const float*)d_in[13]; const float* b3 = (const float*)d_in[14];
  const float* W4 = (const float*)d_in[15]; const float* b4 = (const float*)d_in[16];

  char* ws = (char*)d_ws;
  const size_t MB = 1ull << 20;
  unsigned short* Wp  = (unsigned short*)(ws);            // 4.25MB: 64 x 68KB images
  unsigned short* hf0 = (unsigned short*)(ws + 5 * MB);   // 2MB (chunk layout)
  unsigned short* hb0 = (unsigned short*)(ws + 7 * MB);   // 2MB
  unsigned short* hf1 = (unsigned short*)(ws + 9 * MB);   // 2MB
  unsigned short* hb1 = (unsigned short*)(ws + 11 * MB);  // 2MB
  unsigned short* xt  = (unsigned short*)(ws + 13 * MB);  // 4MB pre-converted x tails
  unsigned* ctrl      = (unsigned*)(ws + 17 * MB);        // rank counters + flags

  hipMemsetAsync(ws + 5 * MB, 0, 4 * MB, stream);    // hf0+hb0 = h(t=0) zeros
  hipMemsetAsync(ws + 17 * MB, 0, 264192, stream);   // ctrl: counters + ring flags

  prep_k<<<1088, 256, 0, stream>>>(Wf_hh, Wf_ih, bf_ih, bf_hh,
                                   Wb_hh, Wb_ih, bb_ih, bb_hh, Wp);
  prep_x<<<1024, 256, 0, stream>>>(y, xt);

  void* args[] = { (void*)&xt, (void*)&Wp,
                   (void*)&hf0, (void*)&hf1, (void*)&hb0, (void*)&hb1, (void*)&ctrl };
  hipLaunchCooperativeKernel((const void*)lstm_persist, dim3(256), dim3(512),
                             args, 0, stream);

  // 128 steps (even): final h lands in buffer 0 for both directions
  heads_k<<<512, 256, 0, stream>>>(hf0, hb0, W1, b1, W2, b2, W3, b3, W4, b4,
                                   (float*)d_out);
}

// Round 22
// 1438.763 us; speedup vs baseline: 1.6767x; 1.6767x over previous
//
#include <hip/hip_runtime.h>

// LSTM_88776974008866: bidirectional LSTM (B=2048, S=128, H=512, in=4) + 4 sigmoid heads.
// Round 22: r19 chassis (wave-decoupled rings, depth-3 A-ring, single-phase poll) +
// r20's xt preconversion ONLY. Disambiguates r20: depth-4 ring caused a 478MB
// write-through anomaly; xt-tail was the likely gain. r21 lesson: any structure holding
// the prefetch rings live across a poll/branch spills (FETCH~WRITE~1.1GB signature) --
// two-phase polling is dead at both block (r17) and wave (r21) level.
// LEDGER: 1 protocol-block/CU (r9/r14); no agent acquire/release in hot loop (r3/r4/r5);
// full-64B-line h writes via chunk layout (r12); VGPR headroom (r10/r15/r21); XCD groups
// via HW_REG_XCC_ID rank (r7); per-(block,wave) rings, no __syncthreads in loop (r19).

typedef __attribute__((ext_vector_type(8))) __bf16 bf16x8;
typedef __attribute__((ext_vector_type(4))) float f32x4;
typedef __attribute__((ext_vector_type(8))) unsigned short u16x8;

__device__ __forceinline__ unsigned short f2bf(float f) {
  unsigned u = __float_as_uint(f);
  u += 0x7fffu + ((u >> 16) & 1u);   // round-to-nearest-even
  return (unsigned short)(u >> 16);
}
__device__ __forceinline__ float bf2f(unsigned short s) {
  return __uint_as_float(((unsigned)s) << 16);
}
__device__ __forceinline__ float sigm(float x) { return 1.0f / (1.0f + __expf(-x)); }
__device__ __forceinline__ float tanhfast(float x) {
  float e = __expf(-2.0f * fabsf(x));
  float t = (1.0f - e) / (1.0f + e);
  return x < 0.0f ? -t : t;
}

__device__ __forceinline__ void gl_lds16(const void* g, void* l) {
  __builtin_amdgcn_global_load_lds(
      (const __attribute__((address_space(1))) unsigned int*)g,
      (__attribute__((address_space(3))) unsigned int*)l, 16, 0, 0);
}

// ---------------------------------------------------------------------------
// prep (r18 verbatim): Whh -> per-(dir,band) 68KB images, 17 K-slices.
// ---------------------------------------------------------------------------
__global__ __launch_bounds__(256) void prep_k(
    const float* __restrict__ Wf_hh, const float* __restrict__ Wf_ih,
    const float* __restrict__ bf_ih, const float* __restrict__ bf_hh,
    const float* __restrict__ Wb_hh, const float* __restrict__ Wb_ih,
    const float* __restrict__ bb_ih, const float* __restrict__ bb_hh,
    unsigned short* __restrict__ Wimg)
{
  int flat = blockIdx.x * 256 + threadIdx.x;   // 0 .. 278527
  int lane = flat & 63;
  int nf = (flat >> 6) & 3;
  int q = flat >> 8;                           // (dir*32+band)*17 + kt
  int kt = q % 17;
  int dn = q / 17;                             // 0..63
  int band = dn & 31;
  int dir = dn >> 5;
  int l15 = lane & 15, lhi = lane >> 4;
  const float* Whh = dir ? Wb_hh : Wf_hh;
  const float* Wih = dir ? Wb_ih : Wf_ih;
  const float* bih = dir ? bb_ih : bf_ih;
  const float* bhh = dir ? bb_hh : bf_hh;

  int j = (band << 4) + l15;                   // hidden index 0..511
  int orig = (nf << 9) + j;                    // gate-major row in [0,2048)

  u16x8 o = {};
  if (kt < 16) {
    int k0 = (kt << 5) + (lhi << 3);
    const float4* src = (const float4*)(Whh + (size_t)orig * 512 + k0);
    float4 a = src[0], b = src[1];
    o[0] = f2bf(a.x); o[1] = f2bf(a.y); o[2] = f2bf(a.z); o[3] = f2bf(a.w);
    o[4] = f2bf(b.x); o[5] = f2bf(b.y); o[6] = f2bf(b.z); o[7] = f2bf(b.w);
  } else if (lhi == 0) {
    o[0] = f2bf(Wih[orig * 4 + 0]);
    o[1] = f2bf(Wih[orig * 4 + 1]);
    o[2] = f2bf(Wih[orig * 4 + 2]);
    o[3] = f2bf(Wih[orig * 4 + 3]);
    o[4] = f2bf(bih[orig] + bhh[orig]);
  }
  *(u16x8*)(Wimg + (size_t)flat * 8) = o;
}

// ---------------------------------------------------------------------------
// prep_x: xt[t][b][8] = {bf16(x0..x3), 1.0, 0,0,0} -- per-step tail A fragment.
// ---------------------------------------------------------------------------
__global__ __launch_bounds__(256) void prep_x(
    const float* __restrict__ y, unsigned short* __restrict__ xt)
{
  int flat = blockIdx.x * 256 + threadIdx.x;   // t*2048 + b, 0..262143
  int b = flat & 2047;
  int t = flat >> 11;
  float4 x4 = ((const float4*)y)[(size_t)b * 128 + t];
  u16x8 o = {};
  o[0] = f2bf(x4.x); o[1] = f2bf(x4.y); o[2] = f2bf(x4.z); o[3] = f2bf(x4.w);
  o[4] = 0x3F80;   // 1.0 -> picks up bias row
  *(u16x8*)(xt + (size_t)flat * 8) = o;
}

__device__ __forceinline__ void mfma8(const bf16x8 av[2], const bf16x8 bv[4],
                                      f32x4 acc[2][4]) {
#pragma unroll
  for (int mf = 0; mf < 2; ++mf)
#pragma unroll
    for (int nf = 0; nf < 4; ++nf)
      acc[mf][nf] = __builtin_amdgcn_mfma_f32_16x16x32_bf16(av[mf], bv[nf], acc[mf][nf], 0, 0, 0);
}

// ---------------------------------------------------------------------------
// Persistent kernel: 256 blocks x 512 threads (1 block/CU via 136KB LDS),
// cooperative launch => exactly 32 blocks per XCD. rank 0..31 = column band.
// h buffers in CHUNK layout: (b,j) at short-index (j>>3)*16384 + b*8 + (j&7).
// Sync: per-(block,wave) flags -> 8 independent 32-wave rings per XCD.
// ctrl (uints): [xcc<<5] rank counters; flags at 256 + ((xcc*8+w)*32 + rank)*32.
// ---------------------------------------------------------------------------
__global__ __launch_bounds__(512, 2) void lstm_persist(
    const unsigned short* __restrict__ xt,
    const unsigned short* __restrict__ Wp,
    unsigned short* __restrict__ hf0, unsigned short* __restrict__ hf1,
    unsigned short* __restrict__ hb0, unsigned short* __restrict__ hb1,
    unsigned* __restrict__ ctrl)
{
  __shared__ alignas(16) unsigned short Wl[69632];   // 136KB: fwd 68KB | bwd 68KB
  __shared__ unsigned rank_sh;

  const int tid = threadIdx.x;
  const int w = tid >> 6, lane = tid & 63;
  const int l15 = lane & 15, lhi = lane >> 4;

  unsigned xcc;
  asm("s_getreg_b32 %0, hwreg(HW_REG_XCC_ID)" : "=s"(xcc));
  xcc &= 7u;

  if (tid == 0) {
    rank_sh = __hip_atomic_fetch_add(ctrl + (xcc << 5), 1u,
                                     __ATOMIC_RELAXED, __HIP_MEMORY_SCOPE_AGENT);
  }
  __syncthreads();
  const int rank = (int)(rank_sh & 31u);   // column band, both dirs
  const int bm0 = (int)xcc << 8;           // this XCD's 256 batch rows

  // ---- one-time: stage both 68KB W images into LDS (17 x 8KB rounds) ----
  for (int i = 0; i < 17; ++i) {
    int c0 = (i << 9) + (w << 6);          // wave-uniform chunk base (4352 % 64 == 0)
    const unsigned short* src =
        (c0 < 4352) ? Wp + ((size_t)rank * 4352 + c0 + lane) * 8
                    : Wp + ((size_t)(32 + rank) * 4352 + (c0 - 4352) + lane) * 8;
    gl_lds16(src, (unsigned short*)Wl + (size_t)c0 * 8);
  }

  float c_reg[16];                          // [dir*8 + mf*4 + r]
#pragma unroll
  for (int i = 0; i < 16; ++i) c_reg[i] = 0.f;

  // per-(xcc, wave) ring of 32 flags, 128B apart
  unsigned* wflags = ctrl + 256 + ((((unsigned)xcc << 3) | (unsigned)w) << 10);
  unsigned* myflag = wflags + ((unsigned)rank << 5);       // single writer

  const unsigned short* wBf = Wl + (lane << 3);            // fwd image base
  const unsigned short* wBb = Wl + 34816 + (lane << 3);    // bwd image base

  __syncthreads();   // Wl ready (drains global_load_lds) -- the ONLY block barrier

#pragma unroll 1
  for (int t = 0; t < 128; ++t) {
    const unsigned short* hf_in = (t & 1) ? hf1 : hf0;
    unsigned short* hf_out      = (t & 1) ? hf0 : hf1;
    const unsigned short* hb_in = (t & 1) ? hb1 : hb0;
    unsigned short* hb_out      = (t & 1) ? hb0 : hb1;

    // ---- tail MFMAs BEFORE the poll (pre-converted xt + B-slice 16 from LDS) ----
    f32x4 accF[2][4], accB[2][4];
#pragma unroll
    for (int a = 0; a < 2; ++a)
#pragma unroll
      for (int b = 0; b < 4; ++b) {
        accF[a][b] = (f32x4){0.f, 0.f, 0.f, 0.f};
        accB[a][b] = (f32x4){0.f, 0.f, 0.f, 0.f};
      }
    {
      bf16x8 atf[2], atb[2], btf[4], btb[4];
      u16x8 z = {};
#pragma unroll
      for (int mf = 0; mf < 2; ++mf) {
        const size_t row = (size_t)(bm0 + (w << 5) + (mf << 4) + l15);
        u16x8 vf = *(const u16x8*)(xt + (((size_t)t << 11) + row) * 8);
        u16x8 vb = *(const u16x8*)(xt + (((size_t)(127 - t) << 11) + row) * 8);
        u16x8 sf = (lhi == 0) ? vf : z;
        u16x8 sb = (lhi == 0) ? vb : z;
        atf[mf] = *(bf16x8*)&sf;
        atb[mf] = *(bf16x8*)&sb;
      }
#pragma unroll
      for (int nf = 0; nf < 4; ++nf) {
        btf[nf] = *(const bf16x8*)(wBf + (16 << 11) + (nf << 9));
        btb[nf] = *(const bf16x8*)(wBb + (16 << 11) + (nf << 9));
      }
      mfma8(atf, btf, accF);
      mfma8(atb, btb, accB);
    }

    // ---- per-wave ring poll (32 flags, relaxed loads) + own L1-only inv ----
    if (t) {
      {
        const unsigned* fp = wflags + ((lane & 31) << 5);
        while (true) {
          unsigned v = 0;
          if (lane < 32)
            v = __hip_atomic_load(fp, __ATOMIC_RELAXED, __HIP_MEMORY_SCOPE_AGENT);
          bool ok = (lane < 32) ? (v >= (unsigned)t) : true;
          if (__all(ok)) break;
          __builtin_amdgcn_s_sleep(1);
        }
      }
      asm volatile("buffer_inv sc0\n\ts_waitcnt vmcnt(0)" ::: "memory");

      // A bases in chunk layout: frag (kt, mf) at base + kt*65536 + mf*128 shorts
      const size_t abase = (size_t)lhi * 16384 + (size_t)(bm0 + (w << 5) + l15) * 8;
      const unsigned short* aFb = hf_in + abase;
      const unsigned short* aBb_ = hb_in + abase;

      bf16x8 aF[3][2], aB[3][2], bF[2][4], bB[2][4];   // A ring depth 3 (r19)

#define SL(i) ((rank + (i)) & 15)
#define ALOADF(kk, sl)                                                         \
      do { const unsigned short* p_ = aFb + (size_t)(kk) * 65536;              \
        aF[sl][0] = *(const bf16x8*)(p_);                                      \
        aF[sl][1] = *(const bf16x8*)(p_ + 128); } while (0)
#define ALOADB(kk, sl)                                                         \
      do { const unsigned short* p_ = aBb_ + (size_t)(kk) * 65536;             \
        aB[sl][0] = *(const bf16x8*)(p_);                                      \
        aB[sl][1] = *(const bf16x8*)(p_ + 128); } while (0)
#define BLOADF(kk, sl)                                                         \
      do { const unsigned short* p_ = wBf + ((kk) << 11);                      \
        bF[sl][0] = *(const bf16x8*)(p_);                                      \
        bF[sl][1] = *(const bf16x8*)(p_ + 512);                                \
        bF[sl][2] = *(const bf16x8*)(p_ + 1024);                               \
        bF[sl][3] = *(const bf16x8*)(p_ + 1536); } while (0)
#define BLOADB(kk, sl)                                                         \
      do { const unsigned short* p_ = wBb + ((kk) << 11);                      \
        bB[sl][0] = *(const bf16x8*)(p_);                                      \
        bB[sl][1] = *(const bf16x8*)(p_ + 512);                                \
        bB[sl][2] = *(const bf16x8*)(p_ + 1024);                               \
        bB[sl][3] = *(const bf16x8*)(p_ + 1536); } while (0)

      ALOADF(SL(0), 0); ALOADB(SL(0), 0);
      ALOADF(SL(1), 1); ALOADB(SL(1), 1);
      ALOADF(SL(2), 2); ALOADB(SL(2), 2);
      BLOADF(SL(0), 0); BLOADB(SL(0), 0);
      BLOADF(SL(1), 1); BLOADB(SL(1), 1);

#pragma unroll
      for (int i = 0; i < 16; ++i) {
        __builtin_amdgcn_s_setprio(1);
        mfma8(aF[i % 3], bF[i & 1], accF);
        __builtin_amdgcn_s_setprio(0);
        if (i < 13) ALOADF(SL(i + 3), (i + 3) % 3);
        if (i < 14) BLOADF(SL(i + 2), i & 1);
        __builtin_amdgcn_s_setprio(1);
        mfma8(aB[i % 3], bB[i & 1], accB);
        __builtin_amdgcn_s_setprio(0);
        if (i < 13) ALOADB(SL(i + 3), (i + 3) % 3);
        if (i < 14) BLOADB(SL(i + 2), i & 1);
      }
#undef ALOADF
#undef ALOADB
#undef BLOADF
#undef BLOADB
#undef SL
    }

    // ---- epilogues: lane-local cell updates; chunk-layout h stores ----
    // (b, j=rank*16+l15) -> (2*rank + (l15>>3))*16384 + b*8 + (l15&7)
    {
      const size_t cbase = (size_t)((rank << 1) + (l15 >> 3)) * 16384 + (size_t)(l15 & 7);
#pragma unroll
      for (int mf = 0; mf < 2; ++mf) {
#pragma unroll
        for (int r = 0; r < 4; ++r) {
          const int b = bm0 + (w << 5) + (mf << 4) + (lhi << 2) + r;
          // fwd
          {
            const float ig = sigm(accF[mf][0][r]);
            const float fg = sigm(accF[mf][1][r]);
            const float gg = tanhfast(accF[mf][2][r]);
            const float og = sigm(accF[mf][3][r]);
            const float cn = fg * c_reg[(mf << 2) + r] + ig * gg;
            c_reg[(mf << 2) + r] = cn;
            hf_out[cbase + (size_t)b * 8] = f2bf(og * tanhfast(cn));
          }
          // bwd
          {
            const float ig = sigm(accB[mf][0][r]);
            const float fg = sigm(accB[mf][1][r]);
            const float gg = tanhfast(accB[mf][2][r]);
            const float og = sigm(accB[mf][3][r]);
            const float cn = fg * c_reg[8 + (mf << 2) + r] + ig * gg;
            c_reg[8 + (mf << 2) + r] = cn;
            hb_out[cbase + (size_t)b * 8] = f2bf(og * tanhfast(cn));
          }
        }
      }
    }

    // ---- publish: drain OWN stores -> lane0 bumps OWN (block,wave) flag ----
    if (t != 127) {
      asm volatile("s_waitcnt vmcnt(0)" ::: "memory");   // own h stores in L2
      if (lane == 0) {
        __hip_atomic_fetch_add(myflag, 1u, __ATOMIC_RELAXED,
                               __HIP_MEMORY_SCOPE_AGENT);
      }
    }
  }
}

// ---------------------------------------------------------------------------
// heads: out[b][k] = sigmoid(hf[b]·Wk[0:512] + hb[b]·Wk[512:1024] + bk)
// h buffers in chunk layout: (b,j) at (j>>3)*16384 + b*8 + (j&7).
// ---------------------------------------------------------------------------
__global__ __launch_bounds__(256) void heads_k(
    const unsigned short* __restrict__ hf, const unsigned short* __restrict__ hb,
    const float* __restrict__ W1, const float* __restrict__ b1,
    const float* __restrict__ W2, const float* __restrict__ b2,
    const float* __restrict__ W3, const float* __restrict__ b3,
    const float* __restrict__ W4, const float* __restrict__ b4,
    float* __restrict__ out)
{
  const int wid = threadIdx.x >> 6, lane = threadIdx.x & 63;
  const int b = blockIdx.x * 4 + wid;
  const unsigned short* src = (lane < 32) ? hf : hb;
  const int ll = (lane < 32) ? lane : (lane - 32);
  u16x8 v0 = *(const u16x8*)(src + (size_t)(2 * ll) * 16384 + (size_t)b * 8);
  u16x8 v1 = *(const u16x8*)(src + (size_t)(2 * ll + 1) * 16384 + (size_t)b * 8);
  const int woff = lane << 4;
  float hv[16];
#pragma unroll
  for (int e = 0; e < 8; ++e) { hv[e] = bf2f(v0[e]); hv[8 + e] = bf2f(v1[e]); }
  float s0 = 0.f, s1 = 0.f, s2 = 0.f, s3 = 0.f;
#pragma unroll
  for (int e = 0; e < 16; ++e) {
    float h = hv[e];
    s0 += h * W1[woff + e];
    s1 += h * W2[woff + e];
    s2 += h * W3[woff + e];
    s3 += h * W4[woff + e];
  }
#pragma unroll
  for (int off = 32; off >= 1; off >>= 1) {
    s0 += __shfl_xor(s0, off, 64);
    s1 += __shfl_xor(s1, off, 64);
    s2 += __shfl_xor(s2, off, 64);
    s3 += __shfl_xor(s3, off, 64);
  }
  if (lane == 0) {
    out[b * 4 + 0] = sigm(s0 + b1[0]);
    out[b * 4 + 1] = sigm(s1 + b2[0]);
    out[b * 4 + 2] = sigm(s2 + b3[0]);
    out[b * 4 + 3] = sigm(s3 + b4[0]);
  }
}

// ---------------------------------------------------------------------------
extern "C" void kernel_launch(void* const* d_in, const int* in_sizes, int n_in,
                              void* d_out, int out_size, void* d_ws, size_t ws_size,
                              hipStream_t stream) {
  (void)in_sizes; (void)n_in; (void)out_size; (void)ws_size;
  const float* y     = (const float*)d_in[0];
  const float* Wf_ih = (const float*)d_in[1];
  const float* Wf_hh = (const float*)d_in[2];
  const float* bf_ih = (const float*)d_in[3];
  const float* bf_hh = (const float*)d_in[4];
  const float* Wb_ih = (const float*)d_in[5];
  const float* Wb_hh = (const float*)d_in[6];
  const float* bb_ih = (const float*)d_in[7];
  const float* bb_hh = (const float*)d_in[8];
  const float* W1 = (const float*)d_in[9];  const float* b1 = (const float*)d_in[10];
  const float* W2 = (const float*)d_in[11]; const float* b2 = (const float*)d_in[12];
  const float* W3 = (const float*)d_in[13]; const float* b3 = (const float*)d_in[14];
  const float* W4 = (const float*)d_in[15]; const float* b4 = (const float*)d_in[16];

  char* ws = (char*)d_ws;
  const size_t MB = 1ull << 20;
  unsigned short* Wp  = (unsigned short*)(ws);            // 4.25MB: 64 x 68KB images
  unsigned short* hf0 = (unsigned short*)(ws + 5 * MB);   // 2MB (chunk layout)
  unsigned short* hb0 = (unsigned short*)(ws + 7 * MB);   // 2MB
  unsigned short* hf1 = (unsigned short*)(ws + 9 * MB);   // 2MB
  unsigned short* hb1 = (unsigned short*)(ws + 11 * MB);  // 2MB
  unsigned short* xt  = (unsigned short*)(ws + 13 * MB);  // 4MB pre-converted x tails
  unsigned* ctrl      = (unsigned*)(ws + 17 * MB);        // rank counters + flags

  hipMemsetAsync(ws + 5 * MB, 0, 4 * MB, stream);    // hf0+hb0 = h(t=0) zeros
  hipMemsetAsync(ws + 17 * MB, 0, 264192, stream);   // ctrl: counters + ring flags

  prep_k<<<1088, 256, 0, stream>>>(Wf_hh, Wf_ih, bf_ih, bf_hh,
                                   Wb_hh, Wb_ih, bb_ih, bb_hh, Wp);
  prep_x<<<1024, 256, 0, stream>>>(y, xt);

  void* args[] = { (void*)&xt, (void*)&Wp,
                   (void*)&hf0, (void*)&hf1, (void*)&hb0, (void*)&hb1, (void*)&ctrl };
  hipLaunchCooperativeKernel((const void*)lstm_persist, dim3(256), dim3(512),
                             args, 0, stream);

  // 128 steps (even): final h lands in buffer 0 for both directions
  heads_k<<<512, 256, 0, stream>>>(hf0, hb0, W1, b1, W2, b2, W3, b3, W4, b4,
                                   (float*)d_out);
}